// Round 4
// baseline (923.623 us; speedup 1.0000x reference)
//
#include <hip/hip_runtime.h>

#define HIDDEN 128
#define NRAD 6
#define W3LD 136   // padded W3 row stride in shorts (272 B) -> benign 2-way LDS aliasing

typedef short bf16x8 __attribute__((ext_vector_type(8)));
typedef float f32x4 __attribute__((ext_vector_type(4)));

__device__ __forceinline__ float fast_rcp(float x) {
    return __builtin_amdgcn_rcpf(x);
}

__device__ __forceinline__ float swishf(float v) {
    return v * fast_rcp(1.0f + __expf(-v));
}

// float -> bf16 (round-to-nearest-even)
__device__ __forceinline__ short f2bf(float f) {
    union { float f; unsigned u; } c; c.f = f;
    unsigned r = (c.u + 0x7FFFu + ((c.u >> 16) & 1u)) >> 16;
    return (short)(unsigned short)r;
}

// P1[a][h] = b_lin[h] + sum_k emb[a][k] * w_lin[h][k]        (k in [0,128))
// P2[a][h] =            sum_k emb[a][k] * w_lin[h][128+k]
__global__ void precompute_kernel(const float* __restrict__ emb,
                                  const float* __restrict__ w_lin,
                                  const float* __restrict__ b_lin,
                                  float* __restrict__ P1,
                                  float* __restrict__ P2) {
    __shared__ __align__(16) float erow[HIDDEN];
    const int a = blockIdx.x;
    const int h = threadIdx.x;
    erow[h] = emb[a * HIDDEN + h];
    __syncthreads();
    float acc1 = b_lin[h];
    float acc2 = 0.f;
    const float* __restrict__ w1 = w_lin + h * 384;
    const float* __restrict__ w2 = w1 + HIDDEN;
#pragma unroll 8
    for (int k = 0; k < HIDDEN; ++k) {
        acc1 += erow[k] * w1[k];
        acc2 += erow[k] * w2[k];
    }
    P1[a * HIDDEN + h] = acc1;
    P2[a * HIDDEN + h] = acc2;
}

struct MD {
    float2 ra, rb, rc;   // rbf[e][0..5]
    int xi, xj;          // xv[iv[e]], xv[jv[e]]
};

__device__ __forceinline__ MD load_md(int tile, int l15, int n_edges,
                                      const int* __restrict__ iv,
                                      const int* __restrict__ jv,
                                      const int* __restrict__ xv,
                                      const float* __restrict__ rbf) {
    int e = tile * 16 + l15;
    int ecl = (e < n_edges) ? e : (n_edges - 1);
    MD m;
    const float2* rp = reinterpret_cast<const float2*>(rbf + (size_t)ecl * NRAD);
    m.ra = rp[0];
    m.rb = rp[1];
    m.rc = rp[2];
    m.xi = xv[iv[ecl]];
    m.xj = xv[jv[ecl]];
    return m;
}

// Per wave: 16 edges x 128 channels, 8 n-tiles x 4 k-steps of
// mfma_f32_16x16x32_bf16 with TRANSPOSED output: A = W3 (from padded LDS),
// B = rbf0^T (built in-register).  C[h][e]: col = lane&15 = edge,
// row = (lane>>4)*4 + reg = h within tile -> lane owns ONE edge and
// 4 consecutive channels per acc register => float4 stores, no shuffles.
// e2's qd = rbf @ w1^T computed by one extra MFMA per n-tile (K zero-padded).
__global__ __launch_bounds__(256, 3)
void edge_mfma_kernel(const int* __restrict__ xv,
                      const float* __restrict__ rbf,
                      const int* __restrict__ iv,
                      const int* __restrict__ jv,
                      const float* __restrict__ w_rbf0,
                      const float* __restrict__ b_rbf0,
                      const float* __restrict__ w_rbf1,
                      const float* __restrict__ w_lin,
                      const float* __restrict__ P1,
                      const float* __restrict__ P2,
                      float* __restrict__ out_e1,
                      float* __restrict__ out_e2,
                      int n_edges, int tiles_per_block, int n_tiles) {
    __shared__ __align__(16) short w3s[HIDDEN * W3LD];
    __shared__ float w0s[HIDDEN * 9];    // stride 9: lg-groups hit distinct banks
    __shared__ float b0s[HIDDEN];
    __shared__ __align__(16) short w1a[HIDDEN * 8];  // w1 rows as bf16, k-padded to 8

    const int tid = threadIdx.x;

    // ---- stage W3 = w_lin[h][256..383] as bf16 into padded rows ----
    {
        const int h = tid >> 1, kh = tid & 1;
        const float4* src =
            reinterpret_cast<const float4*>(w_lin + h * 384 + 256 + kh * 64);
#pragma unroll
        for (int s = 0; s < 8; ++s) {
            float4 va = src[2 * s];
            float4 vb = src[2 * s + 1];
            bf16x8 fr;
            fr[0] = f2bf(va.x); fr[1] = f2bf(va.y);
            fr[2] = f2bf(va.z); fr[3] = f2bf(va.w);
            fr[4] = f2bf(vb.x); fr[5] = f2bf(vb.y);
            fr[6] = f2bf(vb.z); fr[7] = f2bf(vb.w);
            const int slot = kh * 8 + s;
            *reinterpret_cast<bf16x8*>(&w3s[h * W3LD + slot * 8]) = fr;
        }
    }
    if (tid < HIDDEN) {
#pragma unroll
        for (int r = 0; r < NRAD; ++r)
            w0s[tid * 9 + r] = w_rbf0[tid * NRAD + r];
        b0s[tid] = b_rbf0[tid];
        bf16x8 fr;
#pragma unroll
        for (int r = 0; r < NRAD; ++r) fr[r] = f2bf(w_rbf1[tid * NRAD + r]);
        fr[6] = 0; fr[7] = 0;
        *reinterpret_cast<bf16x8*>(&w1a[tid * 8]) = fr;
    }
    __syncthreads();

    const int wid = tid >> 6;
    const int lane = tid & 63;
    const int l15 = lane & 15;
    const int lg = lane >> 4;

    const int bt = blockIdx.x * tiles_per_block;
    const int btEnd = min(bt + tiles_per_block, n_tiles);

    int t = bt + wid;
    MD cur = load_md(t, l15, n_edges, iv, jv, xv, rbf);

    const f32x4 zero4 = (f32x4){0.f, 0.f, 0.f, 0.f};

    for (; t < btEnd; t += 4) {
        MD nxt = load_md(t + 4, l15, n_edges, iv, jv, xv, rbf);  // hide latency

        // ---- qd = rbf @ w1^T via MFMA: B nonzero only in k=0..5 (lg==0) ----
        bf16x8 rpad = (bf16x8){0, 0, 0, 0, 0, 0, 0, 0};
        if (lg == 0) {
            rpad[0] = f2bf(cur.ra.x); rpad[1] = f2bf(cur.ra.y);
            rpad[2] = f2bf(cur.rb.x); rpad[3] = f2bf(cur.rb.y);
            rpad[4] = f2bf(cur.rc.x); rpad[5] = f2bf(cur.rc.y);
        }
        f32x4 acc2[8];
#pragma unroll
        for (int nt = 0; nt < 8; ++nt) {
            // all lanes read row (nt*16+l15); only lg==0 data reaches nonzero B
            const bf16x8 aw = *reinterpret_cast<const bf16x8*>(
                &w1a[(nt * 16 + l15) * 8]);
            acc2[nt] = __builtin_amdgcn_mfma_f32_16x16x32_bf16(aw, rpad, zero4, 0, 0, 0);
        }

        f32x4 acc[8];
#pragma unroll
        for (int nt = 0; nt < 8; ++nt) acc[nt] = zero4;

#pragma unroll
        for (int ks = 0; ks < 4; ++ks) {
            // B fragment: rbf0^T[k][e=l15], k = ks*32 + lg*8 + j, lane-local math
            bf16x8 rb0;
#pragma unroll
            for (int j = 0; j < 8; ++j) {
                const int k = ks * 32 + lg * 8 + j;
                float tv = b0s[k]
                         + cur.ra.x * w0s[k * 9 + 0] + cur.ra.y * w0s[k * 9 + 1]
                         + cur.rb.x * w0s[k * 9 + 2] + cur.rb.y * w0s[k * 9 + 3]
                         + cur.rc.x * w0s[k * 9 + 4] + cur.rc.y * w0s[k * 9 + 5];
                rb0[j] = f2bf(swishf(tv));
            }
#pragma unroll
            for (int nt = 0; nt < 8; ++nt) {
                const bf16x8 wa = *reinterpret_cast<const bf16x8*>(
                    &w3s[(nt * 16 + l15) * W3LD + (ks * 4 + lg) * 8]);
                acc[nt] = __builtin_amdgcn_mfma_f32_16x16x32_bf16(wa, rb0, acc[nt], 0, 0, 0);
            }
        }

        // ---- epilogue: lane owns edge eb+l15, channels nt*16 + lg*4 + q ----
        const int eg = t * 16 + l15;
        if (eg < n_edges) {
            const float* p1p = P1 + cur.xi * HIDDEN + lg * 4;
            const float* p2p = P2 + cur.xj * HIDDEN + lg * 4;
            float* o1 = out_e1 + (size_t)eg * HIDDEN + lg * 4;
            float* o2 = out_e2 + (size_t)eg * HIDDEN + lg * 4;
#pragma unroll
            for (int nt = 0; nt < 8; ++nt) {
                const f32x4 p1 = *reinterpret_cast<const f32x4*>(p1p + nt * 16);
                const f32x4 p2 = *reinterpret_cast<const f32x4*>(p2p + nt * 16);
                f32x4 v1, v2;
#pragma unroll
                for (int q = 0; q < 4; ++q) {
                    const float s = acc[nt][q] + p1[q] + p2[q];
                    const float e1v = swishf(s);
                    v1[q] = e1v;
                    v2[q] = acc2[nt][q] * e1v;
                }
                __builtin_nontemporal_store(v1, reinterpret_cast<f32x4*>(o1 + nt * 16));
                __builtin_nontemporal_store(v2, reinterpret_cast<f32x4*>(o2 + nt * 16));
            }
        }
        cur = nxt;
    }
}

extern "C" void kernel_launch(void* const* d_in, const int* in_sizes, int n_in,
                              void* d_out, int out_size, void* d_ws, size_t ws_size,
                              hipStream_t stream) {
    const int*   xv     = (const int*)  d_in[0];
    const float* rbf    = (const float*)d_in[1];
    const int*   iv     = (const int*)  d_in[2];
    const int*   jv     = (const int*)  d_in[3];
    const float* emb    = (const float*)d_in[4];
    const float* w_rbf0 = (const float*)d_in[5];
    const float* b_rbf0 = (const float*)d_in[6];
    const float* w_lin  = (const float*)d_in[7];
    const float* b_lin  = (const float*)d_in[8];
    const float* w_rbf1 = (const float*)d_in[9];

    const int n_edges = in_sizes[2];
    const int n_emb_rows = in_sizes[4] / HIDDEN;   // 95

    float* P1 = (float*)d_ws;
    float* P2 = P1 + (size_t)n_emb_rows * HIDDEN;

    float* out_e1 = (float*)d_out;
    float* out_e2 = out_e1 + (size_t)n_edges * HIDDEN;

    precompute_kernel<<<n_emb_rows, HIDDEN, 0, stream>>>(emb, w_lin, b_lin, P1, P2);

    const int n_tiles = (n_edges + 15) / 16;
    const int grid = 768;
    const int tpb = (n_tiles + grid - 1) / grid;
    edge_mfma_kernel<<<grid, 256, 0, stream>>>(xv, rbf, iv, jv,
                                               w_rbf0, b_rbf0, w_rbf1, w_lin,
                                               P1, P2, out_e1, out_e2,
                                               n_edges, tpb, n_tiles);
}

// Round 5
// 872.905 us; speedup vs baseline: 1.0581x; 1.0581x over previous
//
#include <hip/hip_runtime.h>

#define HIDDEN 128
#define NRAD 6
#define W3LD 136   // padded W3 row stride in shorts (272 B) -> benign 2-way LDS aliasing

typedef short bf16x8 __attribute__((ext_vector_type(8)));
typedef float f32x4 __attribute__((ext_vector_type(4)));

__device__ __forceinline__ float fast_rcp(float x) {
    return __builtin_amdgcn_rcpf(x);
}

__device__ __forceinline__ float swishf(float v) {
    return v * fast_rcp(1.0f + __expf(-v));
}

// float -> bf16 (round-to-nearest-even)
__device__ __forceinline__ short f2bf(float f) {
    union { float f; unsigned u; } c; c.f = f;
    unsigned r = (c.u + 0x7FFFu + ((c.u >> 16) & 1u)) >> 16;
    return (short)(unsigned short)r;
}

// P1[a][h] = b_lin[h] + sum_k emb[a][k] * w_lin[h][k]        (k in [0,128))
// P2[a][h] =            sum_k emb[a][k] * w_lin[h][128+k]
__global__ void precompute_kernel(const float* __restrict__ emb,
                                  const float* __restrict__ w_lin,
                                  const float* __restrict__ b_lin,
                                  float* __restrict__ P1,
                                  float* __restrict__ P2) {
    __shared__ __align__(16) float erow[HIDDEN];
    const int a = blockIdx.x;
    const int h = threadIdx.x;
    erow[h] = emb[a * HIDDEN + h];
    __syncthreads();
    float acc1 = b_lin[h];
    float acc2 = 0.f;
    const float* __restrict__ w1 = w_lin + h * 384;
    const float* __restrict__ w2 = w1 + HIDDEN;
#pragma unroll 8
    for (int k = 0; k < HIDDEN; ++k) {
        acc1 += erow[k] * w1[k];
        acc2 += erow[k] * w2[k];
    }
    P1[a * HIDDEN + h] = acc1;
    P2[a * HIDDEN + h] = acc2;
}

struct MD {
    float2 ra, rb, rc;   // rbf[e][0..5]
    int xi, xj;          // xv[iv[e]], xv[jv[e]]
};

__device__ __forceinline__ MD load_md(int tile, int l15, int n_edges,
                                      const int* __restrict__ iv,
                                      const int* __restrict__ jv,
                                      const int* __restrict__ xv,
                                      const float* __restrict__ rbf) {
    int e = tile * 16 + l15;
    int ecl = (e < n_edges) ? e : (n_edges - 1);
    MD m;
    const float2* rp = reinterpret_cast<const float2*>(rbf + (size_t)ecl * NRAD);
    m.ra = rp[0];
    m.rb = rp[1];
    m.rc = rp[2];
    m.xi = xv[iv[ecl]];
    m.xj = xv[jv[ecl]];
    return m;
}

// Per wave: 16 edges x 128 channels, 8 n-tiles x 4 k-steps of
// mfma_f32_16x16x32_bf16 with TRANSPOSED output: A = W3 (from padded LDS),
// B = rbf0^T (built in-register).  C[h][e]: col = lane&15 = edge,
// row = (lane>>4)*4 + reg = h within tile -> lane owns ONE edge and
// 4 consecutive channels per acc register => float4 stores, no shuffles.
// e2's qd = rbf @ w1^T computed by one extra MFMA per n-tile (K zero-padded).
__global__ __launch_bounds__(256, 3)
void edge_mfma_kernel(const int* __restrict__ xv,
                      const float* __restrict__ rbf,
                      const int* __restrict__ iv,
                      const int* __restrict__ jv,
                      const float* __restrict__ w_rbf0,
                      const float* __restrict__ b_rbf0,
                      const float* __restrict__ w_rbf1,
                      const float* __restrict__ w_lin,
                      const float* __restrict__ P1,
                      const float* __restrict__ P2,
                      float* __restrict__ out_e1,
                      float* __restrict__ out_e2,
                      int n_edges, int tiles_per_block, int n_tiles) {
    __shared__ __align__(16) short w3s[HIDDEN * W3LD];
    __shared__ float w0s[HIDDEN * 9];    // stride 9: lg-groups hit distinct banks
    __shared__ float b0s[HIDDEN];
    __shared__ __align__(16) short w1a[HIDDEN * 8];  // w1 rows as bf16, k-padded to 8

    const int tid = threadIdx.x;

    // ---- stage W3 = w_lin[h][256..383] as bf16 into padded rows ----
    {
        const int h = tid >> 1, kh = tid & 1;
        const float4* src =
            reinterpret_cast<const float4*>(w_lin + h * 384 + 256 + kh * 64);
#pragma unroll
        for (int s = 0; s < 8; ++s) {
            float4 va = src[2 * s];
            float4 vb = src[2 * s + 1];
            bf16x8 fr;
            fr[0] = f2bf(va.x); fr[1] = f2bf(va.y);
            fr[2] = f2bf(va.z); fr[3] = f2bf(va.w);
            fr[4] = f2bf(vb.x); fr[5] = f2bf(vb.y);
            fr[6] = f2bf(vb.z); fr[7] = f2bf(vb.w);
            const int slot = kh * 8 + s;
            *reinterpret_cast<bf16x8*>(&w3s[h * W3LD + slot * 8]) = fr;
        }
    }
    if (tid < HIDDEN) {
#pragma unroll
        for (int r = 0; r < NRAD; ++r)
            w0s[tid * 9 + r] = w_rbf0[tid * NRAD + r];
        b0s[tid] = b_rbf0[tid];
        bf16x8 fr;
#pragma unroll
        for (int r = 0; r < NRAD; ++r) fr[r] = f2bf(w_rbf1[tid * NRAD + r]);
        fr[6] = 0; fr[7] = 0;
        *reinterpret_cast<bf16x8*>(&w1a[tid * 8]) = fr;
    }
    __syncthreads();

    const int wid = tid >> 6;
    const int lane = tid & 63;
    const int l15 = lane & 15;
    const int lg = lane >> 4;

    const int bt = blockIdx.x * tiles_per_block;
    const int btEnd = min(bt + tiles_per_block, n_tiles);

    int t = bt + wid;
    MD cur = load_md(t, l15, n_edges, iv, jv, xv, rbf);

    const f32x4 zero4 = (f32x4){0.f, 0.f, 0.f, 0.f};

    for (; t < btEnd; t += 4) {
        MD nxt = load_md(t + 4, l15, n_edges, iv, jv, xv, rbf);  // hide latency

        // ---- qd = rbf @ w1^T via MFMA: B nonzero only in k=0..5 (lg==0) ----
        bf16x8 rpad = (bf16x8){0, 0, 0, 0, 0, 0, 0, 0};
        if (lg == 0) {
            rpad[0] = f2bf(cur.ra.x); rpad[1] = f2bf(cur.ra.y);
            rpad[2] = f2bf(cur.rb.x); rpad[3] = f2bf(cur.rb.y);
            rpad[4] = f2bf(cur.rc.x); rpad[5] = f2bf(cur.rc.y);
        }
        f32x4 acc2[8];
#pragma unroll
        for (int nt = 0; nt < 8; ++nt) {
            // all lanes read row (nt*16+l15); only lg==0 data reaches nonzero B
            const bf16x8 aw = *reinterpret_cast<const bf16x8*>(
                &w1a[(nt * 16 + l15) * 8]);
            acc2[nt] = __builtin_amdgcn_mfma_f32_16x16x32_bf16(aw, rpad, zero4, 0, 0, 0);
        }

        f32x4 acc[8];
#pragma unroll
        for (int nt = 0; nt < 8; ++nt) acc[nt] = zero4;

#pragma unroll
        for (int ks = 0; ks < 4; ++ks) {
            // B fragment: rbf0^T[k][e=l15], k = ks*32 + lg*8 + j, lane-local math
            bf16x8 rb0;
#pragma unroll
            for (int j = 0; j < 8; ++j) {
                const int k = ks * 32 + lg * 8 + j;
                float tv = b0s[k]
                         + cur.ra.x * w0s[k * 9 + 0] + cur.ra.y * w0s[k * 9 + 1]
                         + cur.rb.x * w0s[k * 9 + 2] + cur.rb.y * w0s[k * 9 + 3]
                         + cur.rc.x * w0s[k * 9 + 4] + cur.rc.y * w0s[k * 9 + 5];
                rb0[j] = f2bf(swishf(tv));
            }
#pragma unroll
            for (int nt = 0; nt < 8; ++nt) {
                const bf16x8 wa = *reinterpret_cast<const bf16x8*>(
                    &w3s[(nt * 16 + l15) * W3LD + (ks * 4 + lg) * 8]);
                acc[nt] = __builtin_amdgcn_mfma_f32_16x16x32_bf16(wa, rb0, acc[nt], 0, 0, 0);
            }
        }

        // ---- epilogue: lane owns edge eb+l15, channels nt*16 + lg*4 + q ----
        const int eg = t * 16 + l15;
        if (eg < n_edges) {
            const float* p1p = P1 + cur.xi * HIDDEN + lg * 4;
            const float* p2p = P2 + cur.xj * HIDDEN + lg * 4;
            float* o1 = out_e1 + (size_t)eg * HIDDEN + lg * 4;
            float* o2 = out_e2 + (size_t)eg * HIDDEN + lg * 4;
#pragma unroll
            for (int nt = 0; nt < 8; ++nt) {
                const f32x4 p1 = *reinterpret_cast<const f32x4*>(p1p + nt * 16);
                const f32x4 p2 = *reinterpret_cast<const f32x4*>(p2p + nt * 16);
                f32x4 v1, v2;
#pragma unroll
                for (int q = 0; q < 4; ++q) {
                    const float s = acc[nt][q] + p1[q] + p2[q];
                    const float e1v = swishf(s);
                    v1[q] = e1v;
                    v2[q] = acc2[nt][q] * e1v;
                }
                *reinterpret_cast<f32x4*>(o1 + nt * 16) = v1;   // plain cached stores
                *reinterpret_cast<f32x4*>(o2 + nt * 16) = v2;
            }
        }
        cur = nxt;
    }
}

extern "C" void kernel_launch(void* const* d_in, const int* in_sizes, int n_in,
                              void* d_out, int out_size, void* d_ws, size_t ws_size,
                              hipStream_t stream) {
    const int*   xv     = (const int*)  d_in[0];
    const float* rbf    = (const float*)d_in[1];
    const int*   iv     = (const int*)  d_in[2];
    const int*   jv     = (const int*)  d_in[3];
    const float* emb    = (const float*)d_in[4];
    const float* w_rbf0 = (const float*)d_in[5];
    const float* b_rbf0 = (const float*)d_in[6];
    const float* w_lin  = (const float*)d_in[7];
    const float* b_lin  = (const float*)d_in[8];
    const float* w_rbf1 = (const float*)d_in[9];

    const int n_edges = in_sizes[2];
    const int n_emb_rows = in_sizes[4] / HIDDEN;   // 95

    float* P1 = (float*)d_ws;
    float* P2 = P1 + (size_t)n_emb_rows * HIDDEN;

    float* out_e1 = (float*)d_out;
    float* out_e2 = out_e1 + (size_t)n_edges * HIDDEN;

    precompute_kernel<<<n_emb_rows, HIDDEN, 0, stream>>>(emb, w_lin, b_lin, P1, P2);

    const int n_tiles = (n_edges + 15) / 16;
    const int grid = 768;
    const int tpb = (n_tiles + grid - 1) / grid;
    edge_mfma_kernel<<<grid, 256, 0, stream>>>(xv, rbf, iv, jv,
                                               w_rbf0, b_rbf0, w_rbf1, w_lin,
                                               P1, P2, out_e1, out_e2,
                                               n_edges, tpb, n_tiles);
}

// Round 6
// 541.161 us; speedup vs baseline: 1.7067x; 1.6130x over previous
//
#include <hip/hip_runtime.h>

#define HIDDEN 128
#define NRAD 6
#define W3LD 132   // W3 row stride in shorts (264 B): even bank spread, 16B-aligned
#define STGLD 132  // stage row stride in floats (528 B): even bank spread

typedef short bf16x8 __attribute__((ext_vector_type(8)));
typedef float f32x4 __attribute__((ext_vector_type(4)));

__device__ __forceinline__ float fast_rcp(float x) {
    return __builtin_amdgcn_rcpf(x);
}

__device__ __forceinline__ float swishf(float v) {
    return v * fast_rcp(1.0f + __expf(-v));
}

// float -> bf16 (round-to-nearest-even)
__device__ __forceinline__ short f2bf(float f) {
    union { float f; unsigned u; } c; c.f = f;
    unsigned r = (c.u + 0x7FFFu + ((c.u >> 16) & 1u)) >> 16;
    return (short)(unsigned short)r;
}

// P1[a][h] = b_lin[h] + sum_k emb[a][k] * w_lin[h][k]        (k in [0,128))
// P2[a][h] =            sum_k emb[a][k] * w_lin[h][128+k]
__global__ void precompute_kernel(const float* __restrict__ emb,
                                  const float* __restrict__ w_lin,
                                  const float* __restrict__ b_lin,
                                  float* __restrict__ P1,
                                  float* __restrict__ P2) {
    __shared__ __align__(16) float erow[HIDDEN];
    const int a = blockIdx.x;
    const int h = threadIdx.x;
    erow[h] = emb[a * HIDDEN + h];
    __syncthreads();
    float acc1 = b_lin[h];
    float acc2 = 0.f;
    const float* __restrict__ w1 = w_lin + h * 384;
    const float* __restrict__ w2 = w1 + HIDDEN;
#pragma unroll 8
    for (int k = 0; k < HIDDEN; ++k) {
        acc1 += erow[k] * w1[k];
        acc2 += erow[k] * w2[k];
    }
    P1[a * HIDDEN + h] = acc1;
    P2[a * HIDDEN + h] = acc2;
}

struct MD {
    float2 ra, rb, rc;   // rbf[e][0..5]
    int xi, xj;          // xv[iv[e]], xv[jv[e]]
};

__device__ __forceinline__ MD load_md(int tile, int l15, int n_edges,
                                      const int* __restrict__ iv,
                                      const int* __restrict__ jv,
                                      const int* __restrict__ xv,
                                      const float* __restrict__ rbf) {
    int e = tile * 16 + l15;
    int ecl = (e < n_edges) ? e : (n_edges - 1);
    MD m;
    const float2* rp = reinterpret_cast<const float2*>(rbf + (size_t)ecl * NRAD);
    m.ra = rp[0];
    m.rb = rp[1];
    m.rc = rp[2];
    m.xi = xv[iv[ecl]];
    m.xj = xv[jv[ecl]];
    return m;
}

// Per wave: 16 edges x 128 channels, 8 n-tiles x 4 k-steps of
// mfma_f32_16x16x32_bf16, TRANSPOSED output: A = W3 (padded LDS),
// B = rbf0^T (in-register).  C[h][e]: lane owns edge (lane&15) and channels
// nt*16 + (lane>>4)*4 + q.  Epilogue bounces the 16x128 f32 tile through a
// per-wave LDS buffer so every global store is a wave-contiguous 1 KB burst
// (8 full 128 B lines) -> no partial-line RMW traffic at L2.
__global__ __launch_bounds__(256, 2)
void edge_mfma_kernel(const int* __restrict__ xv,
                      const float* __restrict__ rbf,
                      const int* __restrict__ iv,
                      const int* __restrict__ jv,
                      const float* __restrict__ w_rbf0,
                      const float* __restrict__ b_rbf0,
                      const float* __restrict__ w_rbf1,
                      const float* __restrict__ w_lin,
                      const float* __restrict__ P1,
                      const float* __restrict__ P2,
                      float* __restrict__ out_e1,
                      float* __restrict__ out_e2,
                      int n_edges, int tiles_per_block, int n_tiles) {
    __shared__ __align__(16) short w3s[HIDDEN * W3LD];
    __shared__ __align__(16) float stg[4][16 * STGLD];  // per-wave store stage
    __shared__ float w0s[HIDDEN * 9];
    __shared__ float b0s[HIDDEN];
    __shared__ __align__(16) short w1a[HIDDEN * 8];

    const int tid = threadIdx.x;

    // ---- stage W3 = w_lin[h][256..383] as bf16 into padded rows ----
    {
        const int h = tid >> 1, kh = tid & 1;
        const float4* src =
            reinterpret_cast<const float4*>(w_lin + h * 384 + 256 + kh * 64);
#pragma unroll
        for (int s = 0; s < 8; ++s) {
            float4 va = src[2 * s];
            float4 vb = src[2 * s + 1];
            bf16x8 fr;
            fr[0] = f2bf(va.x); fr[1] = f2bf(va.y);
            fr[2] = f2bf(va.z); fr[3] = f2bf(va.w);
            fr[4] = f2bf(vb.x); fr[5] = f2bf(vb.y);
            fr[6] = f2bf(vb.z); fr[7] = f2bf(vb.w);
            const int slot = kh * 8 + s;
            *reinterpret_cast<bf16x8*>(&w3s[h * W3LD + slot * 8]) = fr;
        }
    }
    if (tid < HIDDEN) {
#pragma unroll
        for (int r = 0; r < NRAD; ++r)
            w0s[tid * 9 + r] = w_rbf0[tid * NRAD + r];
        b0s[tid] = b_rbf0[tid];
        bf16x8 fr;
#pragma unroll
        for (int r = 0; r < NRAD; ++r) fr[r] = f2bf(w_rbf1[tid * NRAD + r]);
        fr[6] = 0; fr[7] = 0;
        *reinterpret_cast<bf16x8*>(&w1a[tid * 8]) = fr;
    }
    __syncthreads();

    const int wid = tid >> 6;
    const int lane = tid & 63;
    const int l15 = lane & 15;
    const int lg = lane >> 4;
    float* const mystg = &stg[wid][0];

    const int bt = blockIdx.x * tiles_per_block;
    const int btEnd = min(bt + tiles_per_block, n_tiles);

    int t = bt + wid;
    MD cur = load_md(t, l15, n_edges, iv, jv, xv, rbf);

    const f32x4 zero4 = (f32x4){0.f, 0.f, 0.f, 0.f};

    for (; t < btEnd; t += 4) {
        MD nxt = load_md(t + 4, l15, n_edges, iv, jv, xv, rbf);  // hide latency

        // ---- qd = rbf @ w1^T via MFMA: B nonzero only in k=0..5 (lg==0) ----
        bf16x8 rpad = (bf16x8){0, 0, 0, 0, 0, 0, 0, 0};
        if (lg == 0) {
            rpad[0] = f2bf(cur.ra.x); rpad[1] = f2bf(cur.ra.y);
            rpad[2] = f2bf(cur.rb.x); rpad[3] = f2bf(cur.rb.y);
            rpad[4] = f2bf(cur.rc.x); rpad[5] = f2bf(cur.rc.y);
        }
        f32x4 acc2[8];
#pragma unroll
        for (int nt = 0; nt < 8; ++nt) {
            const bf16x8 aw = *reinterpret_cast<const bf16x8*>(
                &w1a[(nt * 16 + l15) * 8]);
            acc2[nt] = __builtin_amdgcn_mfma_f32_16x16x32_bf16(aw, rpad, zero4, 0, 0, 0);
        }

        f32x4 acc[8];
#pragma unroll
        for (int nt = 0; nt < 8; ++nt) acc[nt] = zero4;

#pragma unroll
        for (int ks = 0; ks < 4; ++ks) {
            // B fragment: rbf0^T[k][e=l15], k = ks*32 + lg*8 + j, lane-local math
            bf16x8 rb0;
#pragma unroll
            for (int j = 0; j < 8; ++j) {
                const int k = ks * 32 + lg * 8 + j;
                float tv = b0s[k]
                         + cur.ra.x * w0s[k * 9 + 0] + cur.ra.y * w0s[k * 9 + 1]
                         + cur.rb.x * w0s[k * 9 + 2] + cur.rb.y * w0s[k * 9 + 3]
                         + cur.rc.x * w0s[k * 9 + 4] + cur.rc.y * w0s[k * 9 + 5];
                rb0[j] = f2bf(swishf(tv));
            }
#pragma unroll
            for (int nt = 0; nt < 8; ++nt) {
                const bf16x8 wa = *reinterpret_cast<const bf16x8*>(
                    &w3s[(nt * 16 + l15) * W3LD + (ks * 4 + lg) * 8]);
                acc[nt] = __builtin_amdgcn_mfma_f32_16x16x32_bf16(wa, rb0, acc[nt], 0, 0, 0);
            }
        }

        // ---- epilogue math in MFMA layout: lane = edge l15, chans nt*16+lg*4 ----
        {
            const float* p1p = P1 + cur.xi * HIDDEN + lg * 4;
            const float* p2p = P2 + cur.xj * HIDDEN + lg * 4;
#pragma unroll
            for (int nt = 0; nt < 8; ++nt) {
                const f32x4 p1 = *reinterpret_cast<const f32x4*>(p1p + nt * 16);
                const f32x4 p2 = *reinterpret_cast<const f32x4*>(p2p + nt * 16);
#pragma unroll
                for (int q = 0; q < 4; ++q) {
                    const float s = acc[nt][q] + p1[q] + p2[q];
                    const float e1v = swishf(s);
                    acc[nt][q] = e1v;            // v1 in place
                    acc2[nt][q] *= e1v;          // v2 in place
                }
            }
        }

        // ---- LDS bounce + full-line stores ----
        const int eb = t * 16;
        const int sedge = lane >> 5;             // 0/1: which edge within a 1 KB burst
        float* const wr = mystg + l15 * STGLD + lg * 4;
        const float* const rd = mystg + sedge * STGLD + (lane & 31) * 4;

        // e1 tile
#pragma unroll
        for (int nt = 0; nt < 8; ++nt)
            *reinterpret_cast<f32x4*>(wr + nt * 16) = acc[nt];
        {
            float* const o1 = out_e1 + (size_t)eb * HIDDEN + lane * 4;
#pragma unroll
            for (int s = 0; s < 8; ++s) {
                const f32x4 v = *reinterpret_cast<const f32x4*>(rd + s * 2 * STGLD);
                if (eb + s * 2 + sedge < n_edges)
                    *reinterpret_cast<f32x4*>(o1 + s * 256) = v;
            }
        }
        // e2 tile (reuse stage; in-order LDS per wave + compiler waitcnts)
#pragma unroll
        for (int nt = 0; nt < 8; ++nt)
            *reinterpret_cast<f32x4*>(wr + nt * 16) = acc2[nt];
        {
            float* const o2 = out_e2 + (size_t)eb * HIDDEN + lane * 4;
#pragma unroll
            for (int s = 0; s < 8; ++s) {
                const f32x4 v = *reinterpret_cast<const f32x4*>(rd + s * 2 * STGLD);
                if (eb + s * 2 + sedge < n_edges)
                    *reinterpret_cast<f32x4*>(o2 + s * 256) = v;
            }
        }
        cur = nxt;
    }
}

extern "C" void kernel_launch(void* const* d_in, const int* in_sizes, int n_in,
                              void* d_out, int out_size, void* d_ws, size_t ws_size,
                              hipStream_t stream) {
    const int*   xv     = (const int*)  d_in[0];
    const float* rbf    = (const float*)d_in[1];
    const int*   iv     = (const int*)  d_in[2];
    const int*   jv     = (const int*)  d_in[3];
    const float* emb    = (const float*)d_in[4];
    const float* w_rbf0 = (const float*)d_in[5];
    const float* b_rbf0 = (const float*)d_in[6];
    const float* w_lin  = (const float*)d_in[7];
    const float* b_lin  = (const float*)d_in[8];
    const float* w_rbf1 = (const float*)d_in[9];

    const int n_edges = in_sizes[2];
    const int n_emb_rows = in_sizes[4] / HIDDEN;   // 95

    float* P1 = (float*)d_ws;
    float* P2 = P1 + (size_t)n_emb_rows * HIDDEN;

    float* out_e1 = (float*)d_out;
    float* out_e2 = out_e1 + (size_t)n_edges * HIDDEN;

    precompute_kernel<<<n_emb_rows, HIDDEN, 0, stream>>>(emb, w_lin, b_lin, P1, P2);

    const int n_tiles = (n_edges + 15) / 16;
    const int grid = 512;                          // 2 blocks/CU (LDS-limited)
    const int tpb = (n_tiles + grid - 1) / grid;
    edge_mfma_kernel<<<grid, 256, 0, stream>>>(xv, rbf, iv, jv,
                                               w_rbf0, b_rbf0, w_rbf1, w_lin,
                                               P1, P2, out_e1, out_e2,
                                               n_edges, tpb, n_tiles);
}

// Round 7
// 268.441 us; speedup vs baseline: 3.4407x; 2.0159x over previous
//
#include <hip/hip_runtime.h>

#define HIDDEN 128
#define NRAD 6
#define NEMB 95
#define PLD 132   // P row stride in ushorts (264 B): rows spread 2*xi banks, 8B-aligned
#define STG 132   // stage row stride in floats

typedef short bf16x8 __attribute__((ext_vector_type(8)));
typedef float f32x4 __attribute__((ext_vector_type(4)));

__device__ __forceinline__ float fast_rcp(float x) {
    return __builtin_amdgcn_rcpf(x);
}
__device__ __forceinline__ float swishf(float v) {
    return v * fast_rcp(1.0f + __expf(-v));
}
// float -> bf16 (round-to-nearest-even)
__device__ __forceinline__ short f2bf(float f) {
    union { float f; unsigned u; } c; c.f = f;
    unsigned r = (c.u + 0x7FFFu + ((c.u >> 16) & 1u)) >> 16;
    return (short)(unsigned short)r;
}
__device__ __forceinline__ float bf2f(unsigned short u) {
    union { unsigned u; float f; } c; c.u = ((unsigned)u) << 16; return c.f;
}

// P1[a][h] = bf16( b_lin[h] + sum_k emb[a][k]*w_lin[h][k]      )  k in [0,128)
// P2[a][h] = bf16(            sum_k emb[a][k]*w_lin[h][128+k]  )
__global__ void precompute_kernel(const float* __restrict__ emb,
                                  const float* __restrict__ w_lin,
                                  const float* __restrict__ b_lin,
                                  unsigned short* __restrict__ P1,
                                  unsigned short* __restrict__ P2) {
    __shared__ __align__(16) float erow[HIDDEN];
    const int a = blockIdx.x;
    const int h = threadIdx.x;
    erow[h] = emb[a * HIDDEN + h];
    __syncthreads();
    float acc1 = b_lin[h];
    float acc2 = 0.f;
    const float* __restrict__ w1 = w_lin + h * 384;
    const float* __restrict__ w2 = w1 + HIDDEN;
#pragma unroll 8
    for (int k = 0; k < HIDDEN; ++k) {
        acc1 += erow[k] * w1[k];
        acc2 += erow[k] * w2[k];
    }
    P1[a * PLD + h] = (unsigned short)f2bf(acc1);
    P2[a * PLD + h] = (unsigned short)f2bf(acc2);
}

struct MD {
    float2 ra, rb, rc;   // rbf[e][0..5]
    int xi, xj;          // xv[iv[e]], xv[jv[e]]
};

__device__ __forceinline__ MD load_md(int tile, int l15, int n_edges,
                                      const int* __restrict__ iv,
                                      const int* __restrict__ jv,
                                      const int* __restrict__ xv,
                                      const float* __restrict__ rbf) {
    int e = tile * 16 + l15;
    int ecl = (e < n_edges) ? e : (n_edges - 1);
    MD m;
    const float2* rp = reinterpret_cast<const float2*>(rbf + (size_t)ecl * NRAD);
    m.ra = rp[0];
    m.rb = rp[1];
    m.rc = rp[2];
    m.xi = xv[iv[ecl]];
    m.xj = xv[jv[ecl]];
    return m;
}

// Block-cooperative: per iteration the 4-wave block processes ONE 16-edge tile.
// Wave w owns channel tiles nt = 2w, 2w+1 (W3 fragments in REGISTERS, 32 VGPR).
// P1/P2 live in LDS as bf16 (no L2 gather traffic).  mfma_f32_16x16x32_bf16,
// transposed output: A = W3 rows (A row = lane&15 + 16*nt), B = rbf0^T
// (B col = edge = lane&15), C[ch][e]: ch = nt*16+(lane>>4)*4+q, e = lane&15.
// Epilogue bounces e1/e2 tiles through shared LDS -> block-flat 4KB-burst stores.
__global__ __launch_bounds__(256, 2)
void edge_mfma_kernel(const int* __restrict__ xv,
                      const float* __restrict__ rbf,
                      const int* __restrict__ iv,
                      const int* __restrict__ jv,
                      const float* __restrict__ w_rbf0,
                      const float* __restrict__ b_rbf0,
                      const float* __restrict__ w_rbf1,
                      const float* __restrict__ w_lin,
                      const unsigned short* __restrict__ P1g,
                      const unsigned short* __restrict__ P2g,
                      float* __restrict__ out_e1,
                      float* __restrict__ out_e2,
                      int n_edges, int tiles_per_block, int n_tiles, int n_rows) {
    __shared__ __align__(16) unsigned short p1s[NEMB * PLD];
    __shared__ __align__(16) unsigned short p2s[NEMB * PLD];
    __shared__ __align__(16) float stg0[16 * STG];   // e1 stage
    __shared__ __align__(16) float stg1[16 * STG];   // e2 stage
    __shared__ float w0s[HIDDEN * 9];
    __shared__ float b0s[HIDDEN];

    const int tid = threadIdx.x;

    // ---- stage P tables into LDS (bf16) ----
    {
        const unsigned* __restrict__ g1 = reinterpret_cast<const unsigned*>(P1g);
        const unsigned* __restrict__ g2 = reinterpret_cast<const unsigned*>(P2g);
        unsigned* s1 = reinterpret_cast<unsigned*>(p1s);
        unsigned* s2 = reinterpret_cast<unsigned*>(p2s);
        const int n = (n_rows < NEMB ? n_rows : NEMB) * PLD / 2;
        for (int s = tid; s < n; s += 256) { s1[s] = g1[s]; s2[s] = g2[s]; }
    }
    if (tid < HIDDEN) {
#pragma unroll
        for (int r = 0; r < NRAD; ++r)
            w0s[tid * 9 + r] = w_rbf0[tid * NRAD + r];
        b0s[tid] = b_rbf0[tid];
    }

    const int wid = tid >> 6;
    const int lane = tid & 63;
    const int l15 = lane & 15;
    const int lg = lane >> 4;

    // ---- W3 + w1 fragments in registers (wave w -> nt = 2w, 2w+1) ----
    bf16x8 w3f[2][4];
    bf16x8 w1f[2];
#pragma unroll
    for (int n2 = 0; n2 < 2; ++n2) {
        const int h = (wid * 2 + n2) * 16 + l15;
        const float* wp = w_lin + h * 384 + 256;
#pragma unroll
        for (int ks = 0; ks < 4; ++ks) {
            const float4* s4 = reinterpret_cast<const float4*>(wp + (ks * 4 + lg) * 8);
            const float4 va = s4[0];
            const float4 vb = s4[1];
            bf16x8 fr;
            fr[0] = f2bf(va.x); fr[1] = f2bf(va.y);
            fr[2] = f2bf(va.z); fr[3] = f2bf(va.w);
            fr[4] = f2bf(vb.x); fr[5] = f2bf(vb.y);
            fr[6] = f2bf(vb.z); fr[7] = f2bf(vb.w);
            w3f[n2][ks] = fr;
        }
        bf16x8 f1;
#pragma unroll
        for (int r = 0; r < NRAD; ++r) f1[r] = f2bf(w_rbf1[h * NRAD + r]);
        f1[6] = 0; f1[7] = 0;
        w1f[n2] = f1;
    }
    __syncthreads();

    const int bt = blockIdx.x * tiles_per_block;
    const int btEnd = min(bt + tiles_per_block, n_tiles);
    if (bt >= btEnd) return;   // uniform per block

    const f32x4 zero4 = (f32x4){0.f, 0.f, 0.f, 0.f};
    MD cur = load_md(bt, l15, n_edges, iv, jv, xv, rbf);

    for (int t = bt; t < btEnd; ++t) {
        MD nxt = load_md(t + 1, l15, n_edges, iv, jv, xv, rbf);  // prefetch

        // ---- qd = rbf @ w1^T via MFMA (B nonzero only k<6, lg==0) ----
        bf16x8 rpad = (bf16x8){0, 0, 0, 0, 0, 0, 0, 0};
        if (lg == 0) {
            rpad[0] = f2bf(cur.ra.x); rpad[1] = f2bf(cur.ra.y);
            rpad[2] = f2bf(cur.rb.x); rpad[3] = f2bf(cur.rb.y);
            rpad[4] = f2bf(cur.rc.x); rpad[5] = f2bf(cur.rc.y);
        }
        f32x4 acc2[2];
#pragma unroll
        for (int n2 = 0; n2 < 2; ++n2)
            acc2[n2] = __builtin_amdgcn_mfma_f32_16x16x32_bf16(w1f[n2], rpad, zero4, 0, 0, 0);

        f32x4 acc[2] = {zero4, zero4};
#pragma unroll
        for (int ks = 0; ks < 4; ++ks) {
            // B fragment: rbf0^T[k][e=l15], k = ks*32 + lg*8 + j (lane-local)
            bf16x8 rb0;
#pragma unroll
            for (int j = 0; j < 8; ++j) {
                const int k = ks * 32 + lg * 8 + j;
                float tv = b0s[k]
                         + cur.ra.x * w0s[k * 9 + 0] + cur.ra.y * w0s[k * 9 + 1]
                         + cur.rb.x * w0s[k * 9 + 2] + cur.rb.y * w0s[k * 9 + 3]
                         + cur.rc.x * w0s[k * 9 + 4] + cur.rc.y * w0s[k * 9 + 5];
                rb0[j] = f2bf(swishf(tv));
            }
#pragma unroll
            for (int n2 = 0; n2 < 2; ++n2)
                acc[n2] = __builtin_amdgcn_mfma_f32_16x16x32_bf16(w3f[n2][ks], rb0, acc[n2], 0, 0, 0);
        }

        // ---- epilogue: P adds from LDS, swish, stage writes ----
#pragma unroll
        for (int n2 = 0; n2 < 2; ++n2) {
            const int ch0 = (wid * 2 + n2) * 16 + lg * 4;
            const uint2 u1 = *reinterpret_cast<const uint2*>(&p1s[cur.xi * PLD + ch0]);
            const uint2 u2 = *reinterpret_cast<const uint2*>(&p2s[cur.xj * PLD + ch0]);
            float pv[4];
            pv[0] = bf2f((unsigned short)(u1.x & 0xffff)) + bf2f((unsigned short)(u2.x & 0xffff));
            pv[1] = bf2f((unsigned short)(u1.x >> 16))    + bf2f((unsigned short)(u2.x >> 16));
            pv[2] = bf2f((unsigned short)(u1.y & 0xffff)) + bf2f((unsigned short)(u2.y & 0xffff));
            pv[3] = bf2f((unsigned short)(u1.y >> 16))    + bf2f((unsigned short)(u2.y >> 16));
            f32x4 v1;
#pragma unroll
            for (int q = 0; q < 4; ++q) {
                const float s = acc[n2][q] + pv[q];
                const float e1v = swishf(s);
                v1[q] = e1v;
                acc2[n2][q] *= e1v;
            }
            *reinterpret_cast<f32x4*>(&stg0[l15 * STG + ch0]) = v1;
            *reinterpret_cast<f32x4*>(&stg1[l15 * STG + ch0]) = acc2[n2];
        }
        __syncthreads();

        // ---- block-flat contiguous stores: 2 x 4KB bursts per array ----
        {
            const size_t base = (size_t)t * 16 * HIDDEN;
#pragma unroll
            for (int s = 0; s < 2; ++s) {
                const int idx = s * 1024 + tid * 4;
                const int e = idx >> 7;
                const f32x4 v1 = *reinterpret_cast<const f32x4*>(&stg0[e * STG + (idx & 127)]);
                const f32x4 v2 = *reinterpret_cast<const f32x4*>(&stg1[e * STG + (idx & 127)]);
                if (t * 16 + e < n_edges) {
                    *reinterpret_cast<f32x4*>(out_e1 + base + idx) = v1;
                    *reinterpret_cast<f32x4*>(out_e2 + base + idx) = v2;
                }
            }
        }
        __syncthreads();
        cur = nxt;
    }
}

extern "C" void kernel_launch(void* const* d_in, const int* in_sizes, int n_in,
                              void* d_out, int out_size, void* d_ws, size_t ws_size,
                              hipStream_t stream) {
    const int*   xv     = (const int*)  d_in[0];
    const float* rbf    = (const float*)d_in[1];
    const int*   iv     = (const int*)  d_in[2];
    const int*   jv     = (const int*)  d_in[3];
    const float* emb    = (const float*)d_in[4];
    const float* w_rbf0 = (const float*)d_in[5];
    const float* b_rbf0 = (const float*)d_in[6];
    const float* w_lin  = (const float*)d_in[7];
    const float* b_lin  = (const float*)d_in[8];
    const float* w_rbf1 = (const float*)d_in[9];

    const int n_edges = in_sizes[2];
    const int n_emb_rows = in_sizes[4] / HIDDEN;   // 95

    unsigned short* P1 = (unsigned short*)d_ws;
    unsigned short* P2 = P1 + (size_t)NEMB * PLD;

    float* out_e1 = (float*)d_out;
    float* out_e2 = out_e1 + (size_t)n_edges * HIDDEN;

    precompute_kernel<<<n_emb_rows, HIDDEN, 0, stream>>>(emb, w_lin, b_lin, P1, P2);

    const int n_tiles = (n_edges + 15) / 16;
    const int grid = 512;                          // 2 blocks/CU (LDS-limited)
    const int tpb = (n_tiles + grid - 1) / grid;
    edge_mfma_kernel<<<grid, 256, 0, stream>>>(xv, rbf, iv, jv,
                                               w_rbf0, b_rbf0, w_rbf1, w_lin,
                                               P1, P2, out_e1, out_e2,
                                               n_edges, tpb, n_tiles, n_emb_rows);
}